// Round 9
// baseline (786.130 us; speedup 1.0000x reference)
//
#include <hip/hip_runtime.h>
#include <hip/hip_bf16.h>

typedef _Float16 f16;
typedef _Float16 f16x8 __attribute__((ext_vector_type(8)));
typedef _Float16 f16x2 __attribute__((ext_vector_type(2)));

#define D 128
#define N_CLS 40
#define BN 128       // nodes per bucket (CSR build)
#define NBMAX 1024   // padded bucket count
#define SW 16        // features per slice (8 slices x 16 = 128)

// ---- 1. bucket histogram of dst (LDS-staged) ----
__global__ __launch_bounds__(256) void k_hist(const int* __restrict__ dst,
                                              int* __restrict__ bcnt, int e) {
  __shared__ int lh[NBMAX];
  for (int j = threadIdx.x; j < NBMAX; j += 256) lh[j] = 0;
  __syncthreads();
  int stride = gridDim.x * blockDim.x;
  for (int q = blockIdx.x * blockDim.x + threadIdx.x; q < e; q += stride)
    atomicAdd(&lh[dst[q] >> 7], 1);
  __syncthreads();
  for (int j = threadIdx.x; j < NBMAX; j += 256)
    if (lh[j]) atomicAdd(&bcnt[j], lh[j]);
}

// ---- 2. exclusive scan of bucket counts ----
__global__ __launch_bounds__(1024) void k_bscan(const int* __restrict__ bcnt,
                                                int* __restrict__ bbase,
                                                int* __restrict__ bcur) {
  __shared__ int sums[NBMAX];
  int t = threadIdx.x;
  int c = bcnt[t];
  sums[t] = c;
  __syncthreads();
  for (int off = 1; off < NBMAX; off <<= 1) {
    int a = (t >= off) ? sums[t - off] : 0;
    __syncthreads();
    sums[t] += a;
    __syncthreads();
  }
  bbase[t] = sums[t] - c;
  bcur[t] = sums[t] - c;
}

// ---- 3. bin edges into bucket-major order ----
__global__ __launch_bounds__(256) void k_place(const int* __restrict__ src,
                                               const int* __restrict__ dst,
                                               int* __restrict__ bcur,
                                               unsigned int* __restrict__ binned,
                                               int e, int nwg) {
  __shared__ int lh[NBMAX];
  __shared__ int lofs[NBMAX];
  __shared__ int lcur[NBMAX];
  int chunk = (e + nwg - 1) / nwg;
  int lo = blockIdx.x * chunk;
  int hi = min(e, lo + chunk);
  int t = threadIdx.x;
  for (int j = t; j < NBMAX; j += 256) { lh[j] = 0; lcur[j] = 0; }
  __syncthreads();
  for (int q = lo + t; q < hi; q += 256) atomicAdd(&lh[dst[q] >> 7], 1);
  __syncthreads();
  for (int j = t; j < NBMAX; j += 256) {
    int c = lh[j];
    lofs[j] = c ? atomicAdd(&bcur[j], c) : 0;
  }
  __syncthreads();
  for (int q = lo + t; q < hi; q += 256) {
    int d = dst[q];
    int b = d >> 7;
    int r = atomicAdd(&lcur[b], 1);
    binned[lofs[b] + r] = ((unsigned int)(d & 127) << 17) | (unsigned int)src[q];
  }
}

// ---- 4. per-bucket counting sort -> CSR + deg + isd + row_start ----
__global__ __launch_bounds__(256) void k_csr(const unsigned int* __restrict__ binned,
                                             const int* __restrict__ bbase,
                                             int* __restrict__ csr,
                                             int* __restrict__ deg,
                                             float* __restrict__ isd,
                                             int* __restrict__ row_start, int n) {
  int b = blockIdx.x;
  int lo = bbase[b], hi = bbase[b + 1];
  __shared__ int h[BN];
  __shared__ int sc[BN];
  __shared__ int cur[BN];
  int t = threadIdx.x;
  if (t < BN) h[t] = 0;
  __syncthreads();
  for (int q = lo + t; q < hi; q += 256) atomicAdd(&h[binned[q] >> 17], 1);
  __syncthreads();
  if (t < BN) sc[t] = h[t];
  __syncthreads();
  for (int off = 1; off < BN; off <<= 1) {
    int a = 0;
    if (t < BN && t >= off) a = sc[t - off];
    __syncthreads();
    if (t < BN) sc[t] += a;
    __syncthreads();
  }
  if (t < BN) {
    int excl = sc[t] - h[t];
    cur[t] = lo + excl;
    int i = b * BN + t;
    if (i < n) {
      deg[i] = h[t];
      isd[i] = rsqrtf((float)(h[t] + 1));
      row_start[i] = lo + excl;
    }
  }
  __syncthreads();
  for (int q = lo + t; q < hi; q += 256) {
    unsigned int u = binned[q];
    int p = atomicAdd(&cur[u >> 17], 1);
    csr[p] = (int)(u & 0x1FFFF);
  }
}

// ---- tiled GEMM: HS = isd[i] * (X @ W), fp32 accum, f16 out (slice-major) ----
// slice-major: elem(node, feat) at (feat>>4)*n*16 + node*16 + (feat&15)
template <bool HALF_IN>
__global__ __launch_bounds__(256) void k_gemm_t(const void* __restrict__ Xv,
                                                const float* __restrict__ W,
                                                const float* __restrict__ isd,
                                                f16* __restrict__ HS, int n) {
  __shared__ float Xt[64][D + 4];
  __shared__ float Wb[32][D + 4];
  int t = threadIdx.x;
  int r0 = blockIdx.x * 64;
  if (!HALF_IN) {
    const float* X = (const float*)Xv;
    for (int q = t; q < 64 * 32; q += 256) {
      int row = q >> 5, cb = (q & 31) << 2;
      float4 v = {0.f, 0.f, 0.f, 0.f};
      if (r0 + row < n) v = *(const float4*)(X + (size_t)(r0 + row) * D + cb);
      *(float4*)&Xt[row][cb] = v;
    }
  } else {
    const f16* X = (const f16*)Xv;  // slice-major
    for (int q = t; q < 64 * 16; q += 256) {
      int row = q >> 4, cb = (q & 15) << 3;  // features cb..cb+7
      f16x8 v = 0;
      if (r0 + row < n)
        v = *(const f16x8*)(X + (size_t)(cb >> 4) * n * SW +
                            ((size_t)(r0 + row) << 4) + (cb & 8));
      float* xp = &Xt[row][cb];
#pragma unroll
      for (int j = 0; j < 8; ++j) xp[j] = (float)v[j];
    }
  }
  int tr = ((t >> 4) & 15) << 2;
  int tc = (t & 15) << 3;
  float acc[4][8];
#pragma unroll
  for (int i = 0; i < 4; ++i)
#pragma unroll
    for (int j = 0; j < 8; ++j) acc[i][j] = 0.f;

  for (int hh = 0; hh < 4; ++hh) {
    __syncthreads();
    for (int q = t; q < 32 * 32; q += 256) {
      int row = q >> 5, cb = (q & 31) << 2;
      *(float4*)&Wb[row][cb] = *(const float4*)(W + (size_t)(hh * 32 + row) * D + cb);
    }
    __syncthreads();
#pragma unroll 4
    for (int k = 0; k < 32; ++k) {
      float4 u0 = *(const float4*)&Wb[k][tc];
      float4 u1 = *(const float4*)&Wb[k][tc + 4];
      float bv[8] = {u0.x, u0.y, u0.z, u0.w, u1.x, u1.y, u1.z, u1.w};
      int kk = hh * 32 + k;
#pragma unroll
      for (int i = 0; i < 4; ++i) {
        float a = Xt[tr + i][kk];
#pragma unroll
        for (int j = 0; j < 8; ++j) acc[i][j] += a * bv[j];
      }
    }
  }
#pragma unroll
  for (int i = 0; i < 4; ++i) {
    int row = r0 + tr + i;
    if (row < n) {
      float s = isd[row];
      f16x8 ov;
#pragma unroll
      for (int j = 0; j < 8; ++j) ov[j] = (f16)(s * acc[i][j]);
      *(f16x8*)(HS + (size_t)(tc >> 4) * n * SW + ((size_t)row << 4) + (tc & 8)) = ov;
    }
  }
}

// ---- sliced aggregation v2: lane=(node j, featpair p); no cross-lane reduce ----
// grid = (n/32) * 8; slice = blockIdx&7 (round-robin -> XCD); 4 waves x 8 nodes/block
__global__ __launch_bounds__(256) void k_aggv(const f16* __restrict__ IN,
                                              const int* __restrict__ csr,
                                              const int* __restrict__ row_start,
                                              const int* __restrict__ deg,
                                              const float* __restrict__ isd,
                                              const float* __restrict__ bias,
                                              f16* __restrict__ OUT, int n) {
  int s = blockIdx.x & 7;
  int chunk = blockIdx.x >> 3;
  int lane = threadIdx.x & 63;
  int p = lane & 7;                     // feature pair: feats s*16 + 2p, 2p+1
  int i = chunk * 32 + ((threadIdx.x >> 6) << 3) + (lane >> 3);
  if (i >= n) return;
  const f16* T = IN + (size_t)s * n * SW;
  int c = deg[i];
  int start = row_start[i];
  float a0 = 0.f, a1 = 0.f;
  for (int e0 = 0; e0 < c; e0 += 8) {
    int kend = min(8, c - e0);                     // uniform within 8-lane group
    int idx = csr[start + e0 + min(p, kend - 1)];  // clamped; clamped lanes never sourced
    f16x2 acc16 = {(f16)0, (f16)0};
    for (int k = 0; k < kend; ++k) {
      int sk = __shfl(idx, (lane & 56) + k);
      acc16 += *(const f16x2*)(T + ((size_t)sk << 4) + (p << 1));
    }
    a0 += (float)acc16[0];
    a1 += (float)acc16[1];
  }
  f16x2 sv = *(const f16x2*)(T + ((size_t)i << 4) + (p << 1));  // self-loop row
  float di = isd[i];
  float2 bb = *(const float2*)(bias + s * SW + (p << 1));
  float v0 = di * (a0 + (float)sv[0]) + bb.x;
  float v1 = di * (a1 + (float)sv[1]) + bb.y;
  f16x2 ov;
  ov[0] = (f16)(v0 > 0.f ? v0 : 0.f);
  ov[1] = (f16)(v1 > 0.f ? v1 : 0.f);
  *(f16x2*)(OUT + (size_t)s * n * SW + ((size_t)i << 4) + (p << 1)) = ov;
}

// ---- classifier: out = T @ Wl + bl (T slice-major f16, out fp32) ----
__global__ __launch_bounds__(256) void k_cls(const f16* __restrict__ T,
                                             const float* __restrict__ Wl,
                                             const float* __restrict__ bl,
                                             float* __restrict__ out, int n) {
  __shared__ float Xt[64][D + 4];
  __shared__ float Wb[D][N_CLS + 8];
  int t = threadIdx.x;
  int r0 = blockIdx.x * 64;
  for (int chunk = t; chunk < 64 * 16; chunk += 256) {
    int row = chunk >> 4, cb = (chunk & 15) << 3;
    f16x8 v = 0;
    if (r0 + row < n)
      v = *(const f16x8*)(T + (size_t)(cb >> 4) * n * SW +
                          ((size_t)(r0 + row) << 4) + (cb & 8));
    float* xp = &Xt[row][cb];
#pragma unroll
    for (int j = 0; j < 8; ++j) xp[j] = (float)v[j];
  }
  for (int q2 = t; q2 < D * N_CLS; q2 += 256) {
    int k = q2 / N_CLS, o = q2 - k * N_CLS;
    Wb[k][o] = Wl[q2];
  }
  __syncthreads();
  int row = t >> 2;   // 64 rows
  int cg = t & 3;     // 4 groups x 10 outputs
  float acc[10];
#pragma unroll
  for (int j = 0; j < 10; ++j) acc[j] = bl[cg * 10 + j];
  for (int k = 0; k < D; ++k) {
    float xv = Xt[row][k];
#pragma unroll
    for (int j = 0; j < 10; ++j) acc[j] += xv * Wb[k][cg * 10 + j];
  }
  if (r0 + row < n) {
    float* op = out + (size_t)(r0 + row) * N_CLS + cg * 10;
#pragma unroll
    for (int j = 0; j < 10; ++j) op[j] = acc[j];
  }
}

extern "C" void kernel_launch(void* const* d_in, const int* in_sizes, int n_in,
                              void* d_out, int out_size, void* d_ws, size_t ws_size,
                              hipStream_t stream) {
  const float* x  = (const float*)d_in[0];
  const int*   ei = (const int*)d_in[1];
  const float* W1 = (const float*)d_in[2];
  const float* b1 = (const float*)d_in[3];
  const float* W2 = (const float*)d_in[4];
  const float* b2 = (const float*)d_in[5];
  const float* Wl = (const float*)d_in[6];
  const float* bl = (const float*)d_in[7];
  float* out = (float*)d_out;

  const int n = in_sizes[0] / D;  // 100000
  const int e = in_sizes[1] / 2;  // 3200000
  const int* src = ei;
  const int* dst = ei + e;
  const int nb = (n + BN - 1) / BN;  // 782

  char* ws = (char*)d_ws;
  size_t off = 0;
  auto alloc = [&](size_t bytes) -> void* {
    void* p = ws + off;
    off += (bytes + 255) & ~(size_t)255;
    return p;
  };
  int*   bcnt      = (int*)alloc(NBMAX * 4);
  int*   bbase     = (int*)alloc(NBMAX * 4);
  int*   bcur      = (int*)alloc(NBMAX * 4);
  int*   deg       = (int*)alloc((size_t)n * 4);
  int*   row_start = (int*)alloc((size_t)n * 4);
  float* isd       = (float*)alloc((size_t)n * 4);
  int*   csr       = (int*)alloc((size_t)e * 4);
  f16*   hA        = (f16*)alloc((size_t)n * D * 2);
  f16*   hB        = (f16*)alloc((size_t)n * D * 2);
  unsigned int* binned = (unsigned int*)hA;  // dead before gemm1 writes hA

  hipMemsetAsync(bcnt, 0, NBMAX * 4, stream);

  const int nwg_place = 512;
  k_hist<<<1024, 256, 0, stream>>>(dst, bcnt, e);
  k_bscan<<<1, 1024, 0, stream>>>(bcnt, bbase, bcur);
  k_place<<<nwg_place, 256, 0, stream>>>(src, dst, bcur, binned, e, nwg_place);
  k_csr<<<nb, 256, 0, stream>>>(binned, bbase, csr, deg, isd, row_start, n);

  int gblocks = (n + 63) / 64;
  int achunks = (n + 31) / 32;        // 3125
  int agrid = achunks * 8;            // slice = blockIdx & 7
  // layer 1: x -> hA (slice-major), agg -> hB
  k_gemm_t<false><<<gblocks, 256, 0, stream>>>(x, W1, isd, hA, n);
  k_aggv<<<agrid, 256, 0, stream>>>(hA, csr, row_start, deg, isd, b1, hB, n);
  // layer 2: hB -> hA, agg -> hB, classifier hB -> out
  k_gemm_t<true><<<gblocks, 256, 0, stream>>>(hB, W2, isd, hA, n);
  k_aggv<<<agrid, 256, 0, stream>>>(hA, csr, row_start, deg, isd, b2, hB, n);
  k_cls<<<gblocks, 256, 0, stream>>>(hB, Wl, bl, out, n);
}

// Round 10
// 587.161 us; speedup vs baseline: 1.3389x; 1.3389x over previous
//
#include <hip/hip_runtime.h>
#include <hip/hip_bf16.h>

typedef _Float16 f16;
typedef _Float16 f16x8 __attribute__((ext_vector_type(8)));

#define D 128
#define N_CLS 40
#define BN 128        // nodes per bucket
#define NBMAX 1024    // padded bucket count
#define CAP 4608      // fixed bucket capacity (mean 4092, sigma ~64 -> +8 sigma)

// ---- 1. bin edges into fixed-capacity buckets (merged hist+scan+place) ----
__global__ __launch_bounds__(256) void k_place(const int* __restrict__ src,
                                               const int* __restrict__ dst,
                                               int* __restrict__ bcnt,
                                               unsigned int* __restrict__ binned,
                                               int e, int nwg, int nbk) {
  __shared__ int lh[NBMAX];
  __shared__ int lofs[NBMAX];
  __shared__ int lcur[NBMAX];
  int chunk = (e + nwg - 1) / nwg;
  int lo = blockIdx.x * chunk;
  int hi = min(e, lo + chunk);
  int t = threadIdx.x;
  for (int j = t; j < nbk; j += 256) { lh[j] = 0; lcur[j] = 0; }
  __syncthreads();
  for (int q = lo + t; q < hi; q += 256) atomicAdd(&lh[dst[q] >> 7], 1);
  __syncthreads();
  for (int j = t; j < nbk; j += 256) {
    int c = lh[j];
    lofs[j] = c ? atomicAdd(&bcnt[j], c) : 0;  // reserve contiguous range in bucket j
  }
  __syncthreads();
  for (int q = lo + t; q < hi; q += 256) {
    int d = dst[q];
    int b = d >> 7;
    int r = atomicAdd(&lcur[b], 1);
    binned[(size_t)b * CAP + lofs[b] + r] =
        ((unsigned int)(d & 127) << 17) | (unsigned int)src[q];
  }
}

// ---- 2. per-bucket counting sort -> CSR (at fixed base) + deg + isd + row_start ----
__global__ __launch_bounds__(256) void k_csr(const unsigned int* __restrict__ binned,
                                             const int* __restrict__ bcnt,
                                             int* __restrict__ csr,
                                             int* __restrict__ deg,
                                             float* __restrict__ isd,
                                             int* __restrict__ row_start, int n) {
  int b = blockIdx.x;
  int lo = b * CAP;
  int cnt = bcnt[b];
  __shared__ int h[BN];
  __shared__ int sc[BN];
  __shared__ int cur[BN];
  int t = threadIdx.x;
  if (t < BN) h[t] = 0;
  __syncthreads();
  for (int q = t; q < cnt; q += 256) atomicAdd(&h[binned[(size_t)lo + q] >> 17], 1);
  __syncthreads();
  if (t < BN) sc[t] = h[t];
  __syncthreads();
  for (int off = 1; off < BN; off <<= 1) {
    int a = 0;
    if (t < BN && t >= off) a = sc[t - off];
    __syncthreads();
    if (t < BN) sc[t] += a;
    __syncthreads();
  }
  if (t < BN) {
    int excl = sc[t] - h[t];
    cur[t] = lo + excl;
    int i = b * BN + t;
    if (i < n) {
      deg[i] = h[t];
      isd[i] = rsqrtf((float)(h[t] + 1));
      row_start[i] = lo + excl;
    }
  }
  __syncthreads();
  for (int q = t; q < cnt; q += 256) {
    unsigned int u = binned[(size_t)lo + q];
    int p = atomicAdd(&cur[u >> 17], 1);
    csr[p] = (int)(u & 0x1FFFF);
  }
}

// ---- tiled GEMM: HS = isd[i] * (X @ W), fp32 accum, f16 out (row-major) ----
template <bool HALF_IN>
__global__ __launch_bounds__(256) void k_gemm_t(const void* __restrict__ Xv,
                                                const float* __restrict__ W,
                                                const float* __restrict__ isd,
                                                f16* __restrict__ HS, int n) {
  __shared__ float Xt[64][D + 4];
  __shared__ float Wb[32][D + 4];
  int t = threadIdx.x;
  int r0 = blockIdx.x * 64;
  if (!HALF_IN) {
    const float* X = (const float*)Xv;
    for (int q = t; q < 64 * 32; q += 256) {
      int row = q >> 5, cb = (q & 31) << 2;
      float4 v = {0.f, 0.f, 0.f, 0.f};
      if (r0 + row < n) v = *(const float4*)(X + (size_t)(r0 + row) * D + cb);
      *(float4*)&Xt[row][cb] = v;
    }
  } else {
    const f16* X = (const f16*)Xv;
    for (int q = t; q < 64 * 16; q += 256) {
      int row = q >> 4, cb = (q & 15) << 3;
      f16x8 v = 0;
      if (r0 + row < n) v = *(const f16x8*)(X + (size_t)(r0 + row) * D + cb);
      float* xp = &Xt[row][cb];
#pragma unroll
      for (int j = 0; j < 8; ++j) xp[j] = (float)v[j];
    }
  }
  int tr = ((t >> 4) & 15) << 2;
  int tc = (t & 15) << 3;
  float acc[4][8];
#pragma unroll
  for (int i = 0; i < 4; ++i)
#pragma unroll
    for (int j = 0; j < 8; ++j) acc[i][j] = 0.f;

  for (int hh = 0; hh < 4; ++hh) {
    __syncthreads();
    for (int q = t; q < 32 * 32; q += 256) {
      int row = q >> 5, cb = (q & 31) << 2;
      *(float4*)&Wb[row][cb] = *(const float4*)(W + (size_t)(hh * 32 + row) * D + cb);
    }
    __syncthreads();
#pragma unroll 4
    for (int k = 0; k < 32; ++k) {
      float4 u0 = *(const float4*)&Wb[k][tc];
      float4 u1 = *(const float4*)&Wb[k][tc + 4];
      float bv[8] = {u0.x, u0.y, u0.z, u0.w, u1.x, u1.y, u1.z, u1.w};
      int kk = hh * 32 + k;
#pragma unroll
      for (int i = 0; i < 4; ++i) {
        float a = Xt[tr + i][kk];
#pragma unroll
        for (int j = 0; j < 8; ++j) acc[i][j] += a * bv[j];
      }
    }
  }
#pragma unroll
  for (int i = 0; i < 4; ++i) {
    int row = r0 + tr + i;
    if (row < n) {
      float s = isd[row];
      f16x8 ov;
#pragma unroll
      for (int j = 0; j < 8; ++j) ov[j] = (f16)(s * acc[i][j]);
      *(f16x8*)(HS + (size_t)row * D + tc) = ov;
    }
  }
}

// ---- gather core: 4 edges/load, 16B/lane, 2 independent 16-edge runs in flight ----
// lane layout: g = lane>>4 (edge subgroup 0..3), l = lane&15 (features l*8..l*8+7)
__device__ inline void gather8(const f16* __restrict__ HS,
                               const int* __restrict__ csr,
                               int start, int c, int lane, float acc[8]) {
  int g = lane >> 4;
  int l = lane & 15;
  const char* base = (const char*)HS;
  size_t lofs = (size_t)(l << 4);
#pragma unroll
  for (int j = 0; j < 8; ++j) acc[j] = 0.f;

  for (int e0 = 0; e0 < c; e0 += 64) {
    int nb = min(64, c - e0);
    int idx = (lane < nb) ? __builtin_nontemporal_load(&csr[start + e0 + lane]) : 0;
    int kb = 0;
    // double 16-edge runs: 8 independent dwordx4 loads in flight
    for (; kb + 32 <= nb; kb += 32) {
      f16x8 A = 0, B = 0;
#pragma unroll
      for (int k = 0; k < 16; k += 4) {
        int sA = __shfl(idx, kb + k + g);
        int sB = __shfl(idx, kb + 16 + k + g);
        A += *(const f16x8*)(base + (((size_t)sA) << 8) + lofs);
        B += *(const f16x8*)(base + (((size_t)sB) << 8) + lofs);
      }
#pragma unroll
      for (int j = 0; j < 8; ++j) acc[j] += (float)A[j] + (float)B[j];
    }
    // single 16-edge run
    for (; kb + 16 <= nb; kb += 16) {
      f16x8 A = 0;
#pragma unroll
      for (int k = 0; k < 16; k += 4) {
        int s = __shfl(idx, kb + k + g);
        A += *(const f16x8*)(base + (((size_t)s) << 8) + lofs);
      }
#pragma unroll
      for (int j = 0; j < 8; ++j) acc[j] += (float)A[j];
    }
    // tail (<16 edges): masked packed accumulate
    if (kb < nb) {
      f16x8 A = 0;
      for (int k = kb; k < nb; k += 4) {
        int kk = k + g;
        int s = __shfl(idx, kk);
        f16x8 u = *(const f16x8*)(base + (((size_t)s) << 8) + lofs);
        if (kk < nb) A += u;
      }
#pragma unroll
      for (int j = 0; j < 8; ++j) acc[j] += (float)A[j];
    }
  }
#pragma unroll
  for (int j = 0; j < 8; ++j) {
    float v = acc[j];
    v += __shfl_xor(v, 16);
    v += __shfl_xor(v, 32);
    acc[j] = v;
  }
}

// ---- agg + bias + relu -> f16 (one wave per node) ----
__global__ __launch_bounds__(64) void k_agg1(const f16* __restrict__ HS,
                                             const int* __restrict__ csr,
                                             const int* __restrict__ row_start,
                                             const int* __restrict__ deg,
                                             const float* __restrict__ isd,
                                             const float* __restrict__ bias,
                                             f16* __restrict__ G) {
  int i = blockIdx.x;
  int lane = threadIdx.x;
  int l = lane & 15;
  float acc[8];
  gather8(HS, csr, row_start[i], deg[i], lane, acc);
  f16x8 sv = *(const f16x8*)(HS + (size_t)i * D + l * 8);
  float di = isd[i];
  float4 bb0 = *(const float4*)(bias + l * 8);
  float4 bb1 = *(const float4*)(bias + l * 8 + 4);
  float bv[8] = {bb0.x, bb0.y, bb0.z, bb0.w, bb1.x, bb1.y, bb1.z, bb1.w};
  f16x8 ov;
#pragma unroll
  for (int j = 0; j < 8; ++j) {
    float v = di * (acc[j] + (float)sv[j]) + bv[j];
    v = v > 0.f ? v : 0.f;
    ov[j] = (f16)v;
  }
  if ((lane >> 4) == 0) *(f16x8*)(G + (size_t)i * D + l * 8) = ov;
}

// ---- agg + bias + relu + classifier -> fp32 out (one wave per node) ----
__global__ __launch_bounds__(64) void k_agg_cls(const f16* __restrict__ HS,
                                                const int* __restrict__ csr,
                                                const int* __restrict__ row_start,
                                                const int* __restrict__ deg,
                                                const float* __restrict__ isd,
                                                const float* __restrict__ b2,
                                                const float* __restrict__ Wl,
                                                const float* __restrict__ bl,
                                                float* __restrict__ out) {
  int i = blockIdx.x;
  int lane = threadIdx.x;
  int l = lane & 15;
  float acc[8];
  gather8(HS, csr, row_start[i], deg[i], lane, acc);
  f16x8 sv = *(const f16x8*)(HS + (size_t)i * D + l * 8);
  float di = isd[i];
  float4 bb0 = *(const float4*)(b2 + l * 8);
  float4 bb1 = *(const float4*)(b2 + l * 8 + 4);
  float bv[8] = {bb0.x, bb0.y, bb0.z, bb0.w, bb1.x, bb1.y, bb1.z, bb1.w};
  __shared__ float tt[D];
#pragma unroll
  for (int j = 0; j < 8; ++j) {
    float v = di * (acc[j] + (float)sv[j]) + bv[j];
    bv[j] = v > 0.f ? v : 0.f;
  }
  if ((lane >> 4) == 0) {
    *(float4*)&tt[l * 8] = make_float4(bv[0], bv[1], bv[2], bv[3]);
    *(float4*)&tt[l * 8 + 4] = make_float4(bv[4], bv[5], bv[6], bv[7]);
  }
  __syncthreads();
  if (lane < N_CLS) {
    float o = bl[lane];
#pragma unroll 8
    for (int k = 0; k < D; ++k) o += tt[k] * Wl[k * N_CLS + lane];
    out[(size_t)i * N_CLS + lane] = o;
  }
}

extern "C" void kernel_launch(void* const* d_in, const int* in_sizes, int n_in,
                              void* d_out, int out_size, void* d_ws, size_t ws_size,
                              hipStream_t stream) {
  const float* x  = (const float*)d_in[0];
  const int*   ei = (const int*)d_in[1];
  const float* W1 = (const float*)d_in[2];
  const float* b1 = (const float*)d_in[3];
  const float* W2 = (const float*)d_in[4];
  const float* b2 = (const float*)d_in[5];
  const float* Wl = (const float*)d_in[6];
  const float* bl = (const float*)d_in[7];
  float* out = (float*)d_out;

  const int n = in_sizes[0] / D;  // 100000
  const int e = in_sizes[1] / 2;  // 3200000
  const int* src = ei;
  const int* dst = ei + e;
  const int nbk = (n + BN - 1) / BN;  // 782

  char* ws = (char*)d_ws;
  size_t off = 0;
  auto alloc = [&](size_t bytes) -> void* {
    void* p = ws + off;
    off += (bytes + 255) & ~(size_t)255;
    return p;
  };
  int*   bcnt      = (int*)alloc(NBMAX * 4);
  int*   deg       = (int*)alloc((size_t)n * 4);
  int*   row_start = (int*)alloc((size_t)n * 4);
  float* isd       = (float*)alloc((size_t)n * 4);
  int*   csr       = (int*)alloc((size_t)nbk * CAP * 4);  // 14.4 MB
  f16*   hA        = (f16*)alloc((size_t)n * D * 2);
  f16*   hB        = (f16*)alloc((size_t)n * D * 2);
  unsigned int* binned = (unsigned int*)hA;  // 14.4 MB region, dead before gemm1

  hipMemsetAsync(bcnt, 0, NBMAX * 4, stream);

  const int nwg_place = 256;
  k_place<<<nwg_place, 256, 0, stream>>>(src, dst, bcnt, binned, e, nwg_place, nbk);
  k_csr<<<nbk, 256, 0, stream>>>(binned, bcnt, csr, deg, isd, row_start, n);

  int gblocks = (n + 63) / 64;
  // layer 1
  k_gemm_t<false><<<gblocks, 256, 0, stream>>>(x, W1, isd, hA, n);
  k_agg1<<<n, 64, 0, stream>>>(hA, csr, row_start, deg, isd, b1, hB);
  // layer 2 + classifier
  k_gemm_t<true><<<gblocks, 256, 0, stream>>>(hB, W2, isd, hA, n);
  k_agg_cls<<<n, 64, 0, stream>>>(hA, csr, row_start, deg, isd, b2, Wl, bl, out);
}